// Round 5
// baseline (71.522 us; speedup 1.0000x reference)
//
#include <hip/hip_runtime.h>

typedef float f32x4 __attribute__((ext_vector_type(4)));
typedef __bf16 bf16x8 __attribute__((ext_vector_type(8)));
typedef int i32x4 __attribute__((ext_vector_type(4)));
typedef unsigned short u16;
typedef unsigned int u32;

#define ALPHA 0.2f
#define NPACK 2048

__device__ __forceinline__ u16 f2bf(float x) {
    u32 u = __float_as_uint(x);
    u += 0x7FFFu + ((u >> 16) & 1u);   // round-to-nearest-even; inputs are finite
    return (u16)(u >> 16);
}

// ---------------------------------------------------------------------------
// Fused kernel: blocks 0..255 compute Wh = h@W^T (+ e_i/e_j + bf16 Wh^T store);
// blocks 256.. stream adj -> bit-packed adjq concurrently (pure HBM stream).
// adjq layout: u32 index i = ((row*4 + q)*4 + ks)*4 + T ; bit (dt*8+j) of
// adjq[i] = adj[row, q*512 + (4T+dt)*32 + ks*8 + j] != 0.
// => K3's lane (r,ks,quarter q) reads its ENTIRE mask as one i32x4.
// ---------------------------------------------------------------------------
__global__ __launch_bounds__(256) void k_wh_pack(
    const float* __restrict__ hsrc, const float* __restrict__ Wsrc,
    const float* __restrict__ asrc, const int* __restrict__ adj,
    u16* __restrict__ WhbT,          // [8][64][2048] bf16 (f-major, m contiguous)
    float* __restrict__ ei, float* __restrict__ ej,
    u32* __restrict__ adjq)
{
    __shared__ float Wl[64][68];     // [k][o]
    __shared__ float hl[64][68];     // [k][r]
    __shared__ __align__(16) u16 tl[4096];

    const int tid = threadIdx.x;

    if (blockIdx.x >= 256) {
        // ---------------- pack path: 2048 blocks, 2 u32 outputs/thread -----
        int i = (blockIdx.x - 256) * 256 + tid;
        #pragma unroll
        for (int it = 0; it < 2; ++it, i += NPACK * 256) {
            const int T = i & 3, ks = (i >> 2) & 3, q = (i >> 4) & 3;
            const int row = i >> 6;
            const int* base = adj + (size_t)row * 2048 + q * 512 + ks * 8;
            u32 bits = 0;
            #pragma unroll
            for (int dt = 0; dt < 4; ++dt) {
                const int c0 = (4 * T + dt) * 32;
                i32x4 v0 = __builtin_nontemporal_load(
                    reinterpret_cast<const i32x4*>(base + c0));
                i32x4 v1 = __builtin_nontemporal_load(
                    reinterpret_cast<const i32x4*>(base + c0 + 4));
                u32 m = 0;
                m |= (v0[0] != 0) ? 1u : 0u;  m |= (v0[1] != 0) ? 2u : 0u;
                m |= (v0[2] != 0) ? 4u : 0u;  m |= (v0[3] != 0) ? 8u : 0u;
                m |= (v1[0] != 0) ? 16u : 0u; m |= (v1[1] != 0) ? 32u : 0u;
                m |= (v1[2] != 0) ? 64u : 0u; m |= (v1[3] != 0) ? 128u : 0u;
                bits |= m << (dt * 8);
            }
            adjq[i] = bits;
        }
        return;
    }

    // ---------------- K1 path (unchanged, verified) ------------------------
    const int tx = tid & 15, ty = tid >> 4;
    const int R0 = blockIdx.x * 64;

    float acc[4][4] = {};

    for (int kc = 0; kc < 4; ++kc) {
        const int k0 = kc * 64;
        __syncthreads();
        #pragma unroll
        for (int p = 0; p < 4; ++p) {
            int idx = p * 1024 + tid * 4;
            int row = idx >> 6, k = idx & 63;
            float4 wv4 = *reinterpret_cast<const float4*>(&Wsrc[row * 256 + k0 + k]);
            Wl[k + 0][row] = wv4.x; Wl[k + 1][row] = wv4.y;
            Wl[k + 2][row] = wv4.z; Wl[k + 3][row] = wv4.w;
            float4 hv4 = *reinterpret_cast<const float4*>(&hsrc[(size_t)(R0 + row) * 256 + k0 + k]);
            hl[k + 0][row] = hv4.x; hl[k + 1][row] = hv4.y;
            hl[k + 2][row] = hv4.z; hl[k + 3][row] = hv4.w;
        }
        __syncthreads();
        #pragma unroll 4
        for (int k = 0; k < 64; ++k) {
            float4 hv = *reinterpret_cast<const float4*>(&hl[k][4 * ty]);
            float4 wv = *reinterpret_cast<const float4*>(&Wl[k][4 * tx]);
            float hr[4] = {hv.x, hv.y, hv.z, hv.w};
            float wc[4] = {wv.x, wv.y, wv.z, wv.w};
            #pragma unroll
            for (int i = 0; i < 4; ++i)
                #pragma unroll
                for (int j = 0; j < 4; ++j)
                    acc[i][j] = fmaf(hr[i], wc[j], acc[i][j]);
        }
    }

    float4 av_i = *reinterpret_cast<const float4*>(&asrc[4 * tx]);
    float4 av_j = *reinterpret_cast<const float4*>(&asrc[64 + 4 * tx]);
    #pragma unroll
    for (int i = 0; i < 4; ++i) {
        float pi = acc[i][0]*av_i.x + acc[i][1]*av_i.y + acc[i][2]*av_i.z + acc[i][3]*av_i.w;
        float pj = acc[i][0]*av_j.x + acc[i][1]*av_j.y + acc[i][2]*av_j.z + acc[i][3]*av_j.w;
        #pragma unroll
        for (int off = 1; off < 16; off <<= 1) {
            pi += __shfl_xor(pi, off, 64);
            pj += __shfl_xor(pj, off, 64);
        }
        if (tx == 0) {
            ei[R0 + 4 * ty + i] = pi;
            ej[R0 + 4 * ty + i] = pj;
        }
    }

    #pragma unroll
    for (int i = 0; i < 4; ++i)
        #pragma unroll
        for (int j = 0; j < 4; ++j) {
            int row = 4 * tx + j;    // o
            int col = 4 * ty + i;    // r (local m)
            tl[(row * 64 + col) ^ ((row & 7) << 3)] = f2bf(acc[i][j]);
        }
    __syncthreads();
    {
        const int b = blockIdx.x >> 5;
        const int nloc = (blockIdx.x & 31) * 64;
        const int o = tid >> 2, rg = tid & 3;
        #pragma unroll
        for (int c = 0; c < 2; ++c) {
            int u = (o * 64 + rg * 16 + 8 * c) ^ ((o & 7) << 3);
            int4 v = *reinterpret_cast<const int4*>(&tl[u]);
            *reinterpret_cast<int4*>(&WhbT[(size_t)(b * 64 + o) * 2048 + nloc + rg * 16 + 8 * c]) = v;
        }
    }
}

// ---------------------------------------------------------------------------
// K3: 1024 blocks x 4 waves. Wave mq owns 16 rows x 512-col quarter. Each lane
// preloads its FULL adj mask (one i32x4 of bits) -> zero adj traffic in loop.
// 16 fully-unrolled tiles (compile-time bit extraction); ej/Wh from hot L2,
// 2-deep prefetch; 4 waves/SIMD. Denominator = 5th MFMA vs ones-fragment.
// Partial (quarter) accumulators combined through LDS, then normalize+store.
// ---------------------------------------------------------------------------
__global__ __launch_bounds__(256, 4) void k_attn(
    const u32* __restrict__ adjq, const u16* __restrict__ WhbT,
    const float* __restrict__ ei_g, const float* __restrict__ ej_g,
    float* __restrict__ out)
{
    __shared__ float accl[3][64][21];

    const int tid  = threadIdx.x;
    const int lane = tid & 63;
    const int mq   = tid >> 6;          // quarter 0..3
    const int b    = blockIdx.x >> 7;   // 128 row-tiles per batch
    const int n0   = (blockIdx.x & 127) * 16;
    const int r    = lane & 15;         // A row / B f-offset
    const int ks   = lane >> 4;         // k-slot group

    const float* ejp = ej_g + b * 2048 + mq * 512 + ks * 8;
    const u16*   whp = WhbT + (size_t)(b * 64 + r) * 2048 + mq * 512 + ks * 8;

    // whole-loop adj mask for this lane: one 16B load
    const i32x4 W4 = *reinterpret_cast<const i32x4*>(
        &adjq[(size_t)(((b * 2048 + n0 + r) * 4 + mq) * 4 + ks) * 4]);

    // Mj = max_m e_j[b,m] (8 KB, L2-resident; overlaps the mask load)
    float mj = -1e30f;
    #pragma unroll
    for (int i = 0; i < 8; ++i) {
        float4 v = *reinterpret_cast<const float4*>(&ej_g[b * 2048 + (i * 64 + lane) * 4]);
        mj = fmaxf(mj, fmaxf(fmaxf(v.x, v.y), fmaxf(v.z, v.w)));
    }
    #pragma unroll
    for (int off = 1; off < 64; off <<= 1) mj = fmaxf(mj, __shfl_xor(mj, off, 64));

    const float eiv = ei_g[b * 2048 + n0 + r];
    const float xM  = eiv + mj;
    const float M   = fmaxf(xM, ALPHA * xM);   // lrelu(e_i + max e_j) >= row max

    bf16x8 bones;   // B[n=0][k]=1 -> denominator column
    {
        const float o = (r == 0) ? 1.0f : 0.0f;
        #pragma unroll
        for (int j = 0; j < 8; ++j) bones[j] = (__bf16)o;
    }

    f32x4 acc0 = {}, acc1 = {}, acc2 = {}, acc3 = {}, acc4 = {};
    float4 Ae0, Ae1, Be0, Be1;
    bf16x8 Aw0, Aw1, Aw2, Aw3, Bw0, Bw1, Bw2, Bw3;

#define LD(t, e0,e1,w0,w1,w2,w3) { const int mo_ = (t) * 32; \
    e0 = *reinterpret_cast<const float4*>(ejp + mo_); \
    e1 = *reinterpret_cast<const float4*>(ejp + mo_ + 4); \
    w0 = *reinterpret_cast<const bf16x8*>(whp + mo_); \
    w1 = *reinterpret_cast<const bf16x8*>(whp + 32768 + mo_); \
    w2 = *reinterpret_cast<const bf16x8*>(whp + 65536 + mo_); \
    w3 = *reinterpret_cast<const bf16x8*>(whp + 98304 + mo_); }

#define PVAL(mk, ev, dst) { \
    float e_ = eiv + (ev); \
    float lr_ = fmaxf(e_, ALPHA * e_); \
    float p_ = __expf(lr_ - M); \
    dst = (__bf16)((mk) ? p_ : 0.0f); }

#define TILE(t, e0,e1,w0,w1,w2,w3) { \
    const u32 byv = ((u32)W4[(t) >> 2]) >> (((t) & 3) * 8); \
    bf16x8 af; \
    PVAL(byv & 1u,   e0.x, af[0]); PVAL(byv & 2u,   e0.y, af[1]); \
    PVAL(byv & 4u,   e0.z, af[2]); PVAL(byv & 8u,   e0.w, af[3]); \
    PVAL(byv & 16u,  e1.x, af[4]); PVAL(byv & 32u,  e1.y, af[5]); \
    PVAL(byv & 64u,  e1.z, af[6]); PVAL(byv & 128u, e1.w, af[7]); \
    acc0 = __builtin_amdgcn_mfma_f32_16x16x32_bf16(af, w0, acc0, 0, 0, 0); \
    acc1 = __builtin_amdgcn_mfma_f32_16x16x32_bf16(af, w1, acc1, 0, 0, 0); \
    acc2 = __builtin_amdgcn_mfma_f32_16x16x32_bf16(af, w2, acc2, 0, 0, 0); \
    acc3 = __builtin_amdgcn_mfma_f32_16x16x32_bf16(af, w3, acc3, 0, 0, 0); \
    acc4 = __builtin_amdgcn_mfma_f32_16x16x32_bf16(af, bones, acc4, 0, 0, 0); }

#define PAIR(t) \
    TILE(t,   Ae0,Ae1,Aw0,Aw1,Aw2,Aw3); LD((t)+2, Ae0,Ae1,Aw0,Aw1,Aw2,Aw3); \
    TILE((t)+1, Be0,Be1,Bw0,Bw1,Bw2,Bw3); LD((t)+3, Be0,Be1,Bw0,Bw1,Bw2,Bw3);

    LD(0, Ae0,Ae1,Aw0,Aw1,Aw2,Aw3);
    LD(1, Be0,Be1,Bw0,Bw1,Bw2,Bw3);
    PAIR(0); PAIR(2); PAIR(4); PAIR(6); PAIR(8); PAIR(10); PAIR(12);
    TILE(14, Ae0,Ae1,Aw0,Aw1,Aw2,Aw3);
    TILE(15, Be0,Be1,Bw0,Bw1,Bw2,Bw3);

#undef PAIR
#undef TILE
#undef PVAL
#undef LD

    // ---- combine quarters (one barrier) + normalize + store ----
    if (mq != 0) {
        #pragma unroll
        for (int q = 0; q < 4; ++q) {
            accl[mq - 1][lane][q]      = acc0[q];
            accl[mq - 1][lane][4 + q]  = acc1[q];
            accl[mq - 1][lane][8 + q]  = acc2[q];
            accl[mq - 1][lane][12 + q] = acc3[q];
            accl[mq - 1][lane][16 + q] = acc4[q];
        }
    }
    __syncthreads();
    if (mq == 0) {
        #pragma unroll
        for (int w = 0; w < 3; ++w) {
            #pragma unroll
            for (int q = 0; q < 4; ++q) {
                acc0[q] += accl[w][lane][q];
                acc1[q] += accl[w][lane][4 + q];
                acc2[q] += accl[w][lane][8 + q];
                acc3[q] += accl[w][lane][12 + q];
                acc4[q] += accl[w][lane][16 + q];
            }
        }
        #pragma unroll
        for (int q = 0; q < 4; ++q) {
            float d   = __shfl(acc4[q], lane & 48, 64);   // den in f=0 lanes
            float inv = (d > 0.0f) ? 1.0f / d : 0.0f;     // all-masked row -> 0
            const int n = n0 + ks * 4 + q;
            float* op = out + (size_t)(b * 2048 + n) * 64 + r;
            op[0]  = acc0[q] * inv;
            op[16] = acc1[q] * inv;
            op[32] = acc2[q] * inv;
            op[48] = acc3[q] * inv;
        }
    }
}

// ---------------------------------------------------------------------------
extern "C" void kernel_launch(void* const* d_in, const int* in_sizes, int n_in,
                              void* d_out, int out_size, void* d_ws, size_t ws_size,
                              hipStream_t stream)
{
    const float* h   = (const float*)d_in[0];   // [8,2048,256]
    const int*   adj = (const int*)d_in[1];     // [8,2048,2048]
    const float* W   = (const float*)d_in[2];   // [64,256]
    const float* a   = (const float*)d_in[3];   // [1,128]
    float* out = (float*)d_out;                  // [8,2048,64]

    u16*   WhbT = (u16*)d_ws;                                   // 2 MB
    float* ei   = (float*)((char*)d_ws + 2 * 1024 * 1024);      // 64 KB
    float* ej   = ei + 16384;                                   // 64 KB
    u32*   adjq = (u32*)((char*)d_ws + 3 * 1024 * 1024);        // 4 MB

    k_wh_pack<<<dim3(256 + NPACK), dim3(256), 0, stream>>>(h, W, a, adj, WhbT, ei, ej, adjq);
    k_attn<<<dim3(1024), dim3(256), 0, stream>>>(adjq, WhbT, ei, ej, out);
}

// Round 6
// 64.912 us; speedup vs baseline: 1.1018x; 1.1018x over previous
//
#include <hip/hip_runtime.h>

typedef float f32x4 __attribute__((ext_vector_type(4)));
typedef __bf16 bf16x8 __attribute__((ext_vector_type(8)));
typedef int i32x4 __attribute__((ext_vector_type(4)));
typedef unsigned short u16;
typedef unsigned int u32;

#define ALPHA 0.2f

__device__ __forceinline__ u16 f2bf(float x) {
    u32 u = __float_as_uint(x);
    u += 0x7FFFu + ((u >> 16) & 1u);   // RNE; inputs finite
    return (u16)(u >> 16);
}

// ---------------------------------------------------------------------------
// K1: Wh = h @ W^T (fp32 register-tiled), fused e_i/e_j, bf16 Wh^T store.
// 256 blocks x 256 thr. (verified rounds 1-5; ~12 us, ~its 67MB HBM floor)
// ---------------------------------------------------------------------------
__global__ __launch_bounds__(256) void k_wh(
    const float* __restrict__ hsrc, const float* __restrict__ Wsrc,
    const float* __restrict__ asrc,
    u16* __restrict__ WhbT,          // [8][64][2048] bf16 (f-major, m contiguous)
    float* __restrict__ ei, float* __restrict__ ej)
{
    __shared__ float Wl[64][68];
    __shared__ float hl[64][68];
    __shared__ __align__(16) u16 tl[4096];

    const int tid = threadIdx.x;
    const int tx = tid & 15, ty = tid >> 4;
    const int R0 = blockIdx.x * 64;

    float acc[4][4] = {};

    for (int kc = 0; kc < 4; ++kc) {
        const int k0 = kc * 64;
        __syncthreads();
        #pragma unroll
        for (int p = 0; p < 4; ++p) {
            int idx = p * 1024 + tid * 4;
            int row = idx >> 6, k = idx & 63;
            float4 wv4 = *reinterpret_cast<const float4*>(&Wsrc[row * 256 + k0 + k]);
            Wl[k + 0][row] = wv4.x; Wl[k + 1][row] = wv4.y;
            Wl[k + 2][row] = wv4.z; Wl[k + 3][row] = wv4.w;
            float4 hv4 = *reinterpret_cast<const float4*>(&hsrc[(size_t)(R0 + row) * 256 + k0 + k]);
            hl[k + 0][row] = hv4.x; hl[k + 1][row] = hv4.y;
            hl[k + 2][row] = hv4.z; hl[k + 3][row] = hv4.w;
        }
        __syncthreads();
        #pragma unroll 4
        for (int k = 0; k < 64; ++k) {
            float4 hv = *reinterpret_cast<const float4*>(&hl[k][4 * ty]);
            float4 wv = *reinterpret_cast<const float4*>(&Wl[k][4 * tx]);
            float hr[4] = {hv.x, hv.y, hv.z, hv.w};
            float wc[4] = {wv.x, wv.y, wv.z, wv.w};
            #pragma unroll
            for (int i = 0; i < 4; ++i)
                #pragma unroll
                for (int j = 0; j < 4; ++j)
                    acc[i][j] = fmaf(hr[i], wc[j], acc[i][j]);
        }
    }

    float4 av_i = *reinterpret_cast<const float4*>(&asrc[4 * tx]);
    float4 av_j = *reinterpret_cast<const float4*>(&asrc[64 + 4 * tx]);
    #pragma unroll
    for (int i = 0; i < 4; ++i) {
        float pi = acc[i][0]*av_i.x + acc[i][1]*av_i.y + acc[i][2]*av_i.z + acc[i][3]*av_i.w;
        float pj = acc[i][0]*av_j.x + acc[i][1]*av_j.y + acc[i][2]*av_j.z + acc[i][3]*av_j.w;
        #pragma unroll
        for (int off = 1; off < 16; off <<= 1) {
            pi += __shfl_xor(pi, off, 64);
            pj += __shfl_xor(pj, off, 64);
        }
        if (tx == 0) {
            ei[R0 + 4 * ty + i] = pi;
            ej[R0 + 4 * ty + i] = pj;
        }
    }

    #pragma unroll
    for (int i = 0; i < 4; ++i)
        #pragma unroll
        for (int j = 0; j < 4; ++j) {
            int row = 4 * tx + j;    // o
            int col = 4 * ty + i;    // r
            tl[(row * 64 + col) ^ ((row & 7) << 3)] = f2bf(acc[i][j]);
        }
    __syncthreads();
    {
        const int b = blockIdx.x >> 5;
        const int nloc = (blockIdx.x & 31) * 64;
        const int o = tid >> 2, rg = tid & 3;
        #pragma unroll
        for (int c = 0; c < 2; ++c) {
            int u = (o * 64 + rg * 16 + 8 * c) ^ ((o & 7) << 3);
            int4 v = *reinterpret_cast<const int4*>(&tl[u]);
            *reinterpret_cast<int4*>(&WhbT[(size_t)(b * 64 + o) * 2048 + nloc + rg * 16 + 8 * c]) = v;
        }
    }
}

// ---------------------------------------------------------------------------
// K2: masked-softmax attention partials. 512 blocks (8b x 32nt x 2mt) x 256thr.
// Block owns 64 rows x 1024 m. adj streamed ONCE from HBM (only loop VMEM,
// 4-deep register prefetch). Wh panel (64f x 256m, 528B padded rows ->
// conflict-free b128 reads) staged in LDS, 4 panels, loads issued a panel
// early. ej (4KB) staged once. p = adj ? exp(lrelu(ei+ej)-M) : 0; 5th MFMA
// vs ones-fragment accumulates the denominator. Plain stores to per-mt
// partial buffers (no atomics, deterministic).
// ---------------------------------------------------------------------------
__global__ __launch_bounds__(256) void k_attn(
    const int* __restrict__ adj, const u16* __restrict__ WhbT,
    const float* __restrict__ ei_g, const float* __restrict__ ej_g,
    float* __restrict__ nump, float* __restrict__ denp)
{
    __shared__ __align__(16) u16 whl[64 * 264];   // 33 KB panel, row stride 264 u16
    __shared__ __align__(16) float ejl[1024];

    const int tid  = threadIdx.x;
    const int lane = tid & 63;
    const int w    = tid >> 6;
    // XCD-contiguous remap: 512 blocks, each XCD gets one whole batch.
    const int lb = (blockIdx.x & 7) * 64 + (blockIdx.x >> 3);
    const int mt = lb & 1;
    const int nt = (lb >> 1) & 31;
    const int b  = lb >> 6;
    const int r  = lane & 15;
    const int ks = lane >> 4;
    const int m0 = mt * 1024;

    // ---- stage ej (block m-range, 4 KB) ----
    {
        float4 v = *reinterpret_cast<const float4*>(&ej_g[b * 2048 + m0 + tid * 4]);
        *reinterpret_cast<float4*>(&ejl[tid * 4]) = v;
    }

    // ---- panel-0 global loads (32 KB; thread: f=tid>>2, 8 x int4) ----
    const u16* whb = WhbT + (size_t)b * 131072;
    const int sf = tid >> 2;
    const int su = (tid & 3) * 8;
    int4 pv0, pv1, pv2, pv3, pv4, pv5, pv6, pv7;
#define PLOAD(p) { const u16* pp = whb + sf * 2048 + m0 + (p) * 256 + su * 8; \
    pv0 = *reinterpret_cast<const int4*>(pp);      pv1 = *reinterpret_cast<const int4*>(pp + 8); \
    pv2 = *reinterpret_cast<const int4*>(pp + 16); pv3 = *reinterpret_cast<const int4*>(pp + 24); \
    pv4 = *reinterpret_cast<const int4*>(pp + 32); pv5 = *reinterpret_cast<const int4*>(pp + 40); \
    pv6 = *reinterpret_cast<const int4*>(pp + 48); pv7 = *reinterpret_cast<const int4*>(pp + 56); }
#define PWRITE() { char* wp = reinterpret_cast<char*>(whl) + sf * 528 + su * 16; \
    *reinterpret_cast<int4*>(wp)       = pv0; *reinterpret_cast<int4*>(wp + 16)  = pv1; \
    *reinterpret_cast<int4*>(wp + 32)  = pv2; *reinterpret_cast<int4*>(wp + 48)  = pv3; \
    *reinterpret_cast<int4*>(wp + 64)  = pv4; *reinterpret_cast<int4*>(wp + 80)  = pv5; \
    *reinterpret_cast<int4*>(wp + 96)  = pv6; *reinterpret_cast<int4*>(wp + 112) = pv7; }
    PLOAD(0);

    // ---- Mj = max_m e_j[b,m] (L2-resident, overlaps loads above) ----
    float mj = -1e30f;
    #pragma unroll
    for (int i = 0; i < 8; ++i) {
        float4 v = *reinterpret_cast<const float4*>(&ej_g[b * 2048 + (i * 64 + lane) * 4]);
        mj = fmaxf(mj, fmaxf(fmaxf(v.x, v.y), fmaxf(v.z, v.w)));
    }
    #pragma unroll
    for (int off = 1; off < 64; off <<= 1) mj = fmaxf(mj, __shfl_xor(mj, off, 64));

    const float eiv = ei_g[b * 2048 + nt * 64 + w * 16 + r];
    const float xM  = eiv + mj;
    const float M   = fmaxf(xM, ALPHA * xM);   // lrelu(ei + max ej) >= any row score

    bf16x8 bones;
    {
        const float o = (r == 0) ? 1.0f : 0.0f;
        #pragma unroll
        for (int j = 0; j < 8; ++j) bones[j] = (__bf16)o;
    }

    const int* adjp = adj + (size_t)(b * 2048 + nt * 64 + w * 16 + r) * 2048 + m0 + ks * 8;

    // ---- adj rolling prefetch (4 steps deep) ----
    i32x4 Aa0, Aa1, Ba0, Ba1, Ca0, Ca1, Da0, Da1;
#define LADJ(gt, x0, x1) if ((gt) < 32) { \
    x0 = __builtin_nontemporal_load(reinterpret_cast<const i32x4*>(adjp + (gt) * 32)); \
    x1 = __builtin_nontemporal_load(reinterpret_cast<const i32x4*>(adjp + (gt) * 32 + 4)); }
    LADJ(0, Aa0, Aa1); LADJ(1, Ba0, Ba1); LADJ(2, Ca0, Ca1); LADJ(3, Da0, Da1);

    PWRITE();            // panel 0 into LDS
    __syncthreads();

    f32x4 acc0 = {}, acc1 = {}, acc2 = {}, acc3 = {}, acc4 = {};

    const char* wl0 = reinterpret_cast<const char*>(whl) + r * 528 + ks * 16;
    const float* eb = ejl + ks * 8;

#define PVAL(mk, ev, dst) { \
    float e_ = eiv + (ev); \
    float lr_ = fmaxf(e_, ALPHA * e_); \
    float p_ = __expf(lr_ - M); \
    dst = (__bf16)(((mk) != 0) ? p_ : 0.0f); }

#define STEP(gt, x0, x1) { \
    const int tl_ = (gt) & 7; \
    float4 e0 = *reinterpret_cast<const float4*>(eb + (gt) * 32); \
    float4 e1 = *reinterpret_cast<const float4*>(eb + (gt) * 32 + 4); \
    bf16x8 af; \
    PVAL(x0[0], e0.x, af[0]); PVAL(x0[1], e0.y, af[1]); \
    PVAL(x0[2], e0.z, af[2]); PVAL(x0[3], e0.w, af[3]); \
    PVAL(x1[0], e1.x, af[4]); PVAL(x1[1], e1.y, af[5]); \
    PVAL(x1[2], e1.z, af[6]); PVAL(x1[3], e1.w, af[7]); \
    bf16x8 w0 = *reinterpret_cast<const bf16x8*>(wl0 + tl_ * 64); \
    bf16x8 w1 = *reinterpret_cast<const bf16x8*>(wl0 + tl_ * 64 + 16 * 528); \
    bf16x8 w2 = *reinterpret_cast<const bf16x8*>(wl0 + tl_ * 64 + 32 * 528); \
    bf16x8 w3 = *reinterpret_cast<const bf16x8*>(wl0 + tl_ * 64 + 48 * 528); \
    acc0 = __builtin_amdgcn_mfma_f32_16x16x32_bf16(af, w0, acc0, 0, 0, 0); \
    acc1 = __builtin_amdgcn_mfma_f32_16x16x32_bf16(af, w1, acc1, 0, 0, 0); \
    acc2 = __builtin_amdgcn_mfma_f32_16x16x32_bf16(af, w2, acc2, 0, 0, 0); \
    acc3 = __builtin_amdgcn_mfma_f32_16x16x32_bf16(af, w3, acc3, 0, 0, 0); \
    acc4 = __builtin_amdgcn_mfma_f32_16x16x32_bf16(af, bones, acc4, 0, 0, 0); }

    #pragma unroll
    for (int p = 0; p < 4; ++p) {
        if (p < 3) PLOAD(p + 1);                 // next panel: issue early
        STEP(p * 8 + 0, Aa0, Aa1); LADJ(p * 8 + 4,  Aa0, Aa1);
        STEP(p * 8 + 1, Ba0, Ba1); LADJ(p * 8 + 5,  Ba0, Ba1);
        STEP(p * 8 + 2, Ca0, Ca1); LADJ(p * 8 + 6,  Ca0, Ca1);
        STEP(p * 8 + 3, Da0, Da1); LADJ(p * 8 + 7,  Da0, Da1);
        STEP(p * 8 + 4, Aa0, Aa1); LADJ(p * 8 + 8,  Aa0, Aa1);
        STEP(p * 8 + 5, Ba0, Ba1); LADJ(p * 8 + 9,  Ba0, Ba1);
        STEP(p * 8 + 6, Ca0, Ca1); LADJ(p * 8 + 10, Ca0, Ca1);
        STEP(p * 8 + 7, Da0, Da1); LADJ(p * 8 + 11, Da0, Da1);
        if (p < 3) {
            __syncthreads();    // all waves done reading panel p
            PWRITE();           // write panel p+1 (loads landed during compute)
            __syncthreads();
        }
    }
#undef STEP
#undef PVAL
#undef LADJ
#undef PWRITE
#undef PLOAD

    // ---- epilogue: partial num/den stores (coalesced, no atomics) ----
    const size_t nb0 = (size_t)mt * 16384 + b * 2048 + nt * 64 + w * 16;
    #pragma unroll
    for (int q = 0; q < 4; ++q) {
        const int rr = ks * 4 + q;
        float* np = nump + (nb0 + rr) * 64 + r;
        np[0]  = acc0[q];
        np[16] = acc1[q];
        np[32] = acc2[q];
        np[48] = acc3[q];
        if (r == 0) denp[nb0 + rr] = acc4[q];
    }
}

// ---------------------------------------------------------------------------
// K3: combine the 2 m-half partials and normalize. 1024 blocks x 256 thr.
// ---------------------------------------------------------------------------
__global__ __launch_bounds__(256) void k_norm(
    const float* __restrict__ nump, const float* __restrict__ denp,
    float* __restrict__ out)
{
    const int tid = threadIdx.x;
    const int f4 = tid & 15;
    const size_t N = (size_t)blockIdx.x * 16 + (tid >> 4);
    const float d = denp[N] + denp[16384 + N];
    const float inv = (d > 0.0f) ? 1.0f / d : 0.0f;   // all-masked row -> 0
    float4 a = *reinterpret_cast<const float4*>(&nump[N * 64 + f4 * 4]);
    float4 c = *reinterpret_cast<const float4*>(&nump[(16384 + N) * 64 + f4 * 4]);
    float4 o;
    o.x = (a.x + c.x) * inv; o.y = (a.y + c.y) * inv;
    o.z = (a.z + c.z) * inv; o.w = (a.w + c.w) * inv;
    *reinterpret_cast<float4*>(&out[N * 64 + f4 * 4]) = o;
}

// ---------------------------------------------------------------------------
extern "C" void kernel_launch(void* const* d_in, const int* in_sizes, int n_in,
                              void* d_out, int out_size, void* d_ws, size_t ws_size,
                              hipStream_t stream)
{
    const float* h   = (const float*)d_in[0];   // [8,2048,256]
    const int*   adj = (const int*)d_in[1];     // [8,2048,2048]
    const float* W   = (const float*)d_in[2];   // [64,256]
    const float* a   = (const float*)d_in[3];   // [1,128]
    float* out = (float*)d_out;                  // [8,2048,64]

    u16*   WhbT = (u16*)d_ws;                                    // 2 MB
    float* ei   = (float*)((char*)d_ws + 2 * 1024 * 1024);       // 64 KB
    float* ej   = ei + 16384;                                    // 64 KB
    float* nump = (float*)((char*)d_ws + 4 * 1024 * 1024);       // 8 MB [2][16384][64]
    float* denp = (float*)((char*)d_ws + 12 * 1024 * 1024);      // 128 KB [2][16384]

    k_wh  <<<dim3(256),  dim3(256), 0, stream>>>(h, W, a, WhbT, ei, ej);
    k_attn<<<dim3(512),  dim3(256), 0, stream>>>(adj, WhbT, ei, ej, nump, denp);
    k_norm<<<dim3(1024), dim3(256), 0, stream>>>(nump, denp, out);
}